// Round 7
// baseline (139.251 us; speedup 1.0000x reference)
//
#include <hip/hip_runtime.h>

#define HORIZON 20
#define BATCH   524288

typedef float f32x4 __attribute__((ext_vector_type(4)));

__global__ __launch_bounds__(256) void drone_rollout(
    const float* __restrict__ state_in,  // [BATCH,16]
    const float* __restrict__ U,         // [HORIZON,1,4] flat = 80
    float* __restrict__ out)             // [HORIZON,BATCH,16]
{
    constexpr float DT    = 0.05f;
    constexpr float GRAV  = 9.81f;
    constexpr float MAX_T = 5.0f;
    constexpr float ARM   = 0.2f;
    constexpr float KAPPA = 0.02f;
    constexpr float Ix = 0.01f, Iy = 0.01f, Iz = 0.02f;
    constexpr float rIx = 100.0f, rIy = 100.0f, rIz = 50.0f;
    // DT/TAU_M == 1.0f exactly -> thrust update is t += (a*MAX_T - t).

    __shared__ alignas(16) float s_act[HORIZON * 4];  // sigmoid(U)*MAX_T
    __shared__ f32x4 lds4[2][256 * 4];                // 32 KB double buffer

    const int tid = threadIdx.x;
    if (tid < HORIZON * 4) {
        float u = U[tid];
        s_act[tid] = MAX_T / (1.0f + expf(-u));
    }

    const int b = blockIdx.x * 256 + tid;
    const f32x4* sp = reinterpret_cast<const f32x4*>(state_in) + (size_t)b * 4;
    f32x4 s0 = sp[0], s1 = sp[1], s2 = sp[2], s3 = sp[3];
    float px = s0.x, py = s0.y, pz = s0.z;
    float vx = s0.w, vy = s1.x, vz = s1.y;
    float phi = s1.z, th = s1.w, psi = s2.x;
    float p = s2.y, q = s2.z, r = s2.w;
    float t0 = s3.x, t1 = s3.y, t2 = s3.z, t3 = s3.w;

    __syncthreads();   // s_act ready

    // Store-transpose geometry (verified rounds 2-5).
    const int swzw   = (tid >> 1) & 3;                // write-side chunk XOR
    const int rrow   = tid >> 2;                      // read-side base row
    const int rchunk = (tid & 3) ^ ((tid >> 3) & 3);  // read-side swizzled chunk
    f32x4* const outbase = reinterpret_cast<f32x4*>(out)
                         + (size_t)blockIdx.x * 256 * 4;

    #pragma unroll
    for (int t = 0; t < HORIZON; ++t) {
        const f32x4 A = *reinterpret_cast<const f32x4*>(&s_act[t * 4]);

        // rotor thrust first-order lag (dt/tau == 1)
        t0 += A.x - t0;
        t1 += A.y - t1;
        t2 += A.z - t2;
        t3 += A.w - t3;

        const float F    = t0 + t1 + t2 + t3;
        const float taux = ARM * (t0 - t2);
        const float tauy = ARM * (t1 - t3);
        const float tauz = KAPPA * (t0 - t1 + t2 - t3);

        float sphi, cphi, sth, cth, spsi, cpsi;
        __sincosf(phi, &sphi, &cphi);
        __sincosf(th,  &sth,  &cth);
        __sincosf(psi, &spsi, &cpsi);

        const float zbx = cphi * sth * cpsi + sphi * spsi;
        const float zby = cphi * sth * spsi - sphi * cpsi;
        const float zbz = cphi * cth;
        const float ax = F * zbx;          // MASS == 1
        const float ay = F * zby;
        const float az = F * zbz - GRAV;

        const float rcth  = 1.0f / cth;
        const float tanth = sth * rcth;
        const float attd0 = p + sphi * tanth * q + cphi * tanth * r;
        const float attd1 = cphi * q - sphi * r;
        const float attd2 = (sphi * q + cphi * r) * rcth;

        const float hx = Ix * p, hy = Iy * q, hz = Iz * r;
        const float pd = (taux - (q * hz - r * hy)) * rIx;
        const float qd = (tauy - (r * hx - p * hz)) * rIy;
        const float rd = (tauz - (p * hy - q * hx)) * rIz;

        px += DT * vx;  py += DT * vy;  pz += DT * vz;
        vx += DT * ax;  vy += DT * ay;  vz += DT * az;
        phi += DT * attd0;  th += DT * attd1;  psi += DT * attd2;
        p += DT * pd;  q += DT * qd;  r += DT * rd;

        // --- stage this step's state into LDS (swizzled, double-buffered) ---
        const int bb = t & 1;
        f32x4* wb = &lds4[bb][tid * 4];
        wb[0 ^ swzw] = f32x4{px, py, pz, vx};
        wb[1 ^ swzw] = f32x4{vy, vz, phi, th};
        wb[2 ^ swzw] = f32x4{psi, p, q, r};
        wb[3 ^ swzw] = f32x4{t0, t1, t2, t3};
        __syncthreads();

        // --- transposed read-back + lane-contiguous PLAIN global stores ---
        // A/B vs rounds 1-5: no nontemporal flag. Everything else identical
        // to the round-2 best (128.7 us).
        f32x4* const op = outbase + (size_t)t * (BATCH * 4);
        #pragma unroll
        for (int k = 0; k < 4; ++k) {
            f32x4 v = lds4[bb][(k * 64 + rrow) * 4 + rchunk];
            op[k * 256 + tid] = v;
        }
    }
}

extern "C" void kernel_launch(void* const* d_in, const int* in_sizes, int n_in,
                              void* d_out, int out_size, void* d_ws, size_t ws_size,
                              hipStream_t stream) {
    const float* state = (const float*)d_in[0];
    const float* U     = (const float*)d_in[1];
    float* out         = (float*)d_out;

    dim3 block(256);
    dim3 grid(BATCH / 256);
    drone_rollout<<<grid, block, 0, stream>>>(state, U, out);
}

// Round 8
// 129.140 us; speedup vs baseline: 1.0783x; 1.0783x over previous
//
#include <hip/hip_runtime.h>

#define HORIZON 20
#define BATCH   524288

typedef float f32x4 __attribute__((ext_vector_type(4)));

__global__ __launch_bounds__(256) void drone_rollout(
    const float* __restrict__ state_in,  // [BATCH,16]
    const float* __restrict__ U,         // [HORIZON,1,4] flat = 80
    float* __restrict__ out)             // [HORIZON,BATCH,16]
{
    constexpr float DT    = 0.05f;
    constexpr float GRAV  = 9.81f;
    constexpr float MAX_T = 5.0f;
    constexpr float ARM   = 0.2f;
    constexpr float KAPPA = 0.02f;
    constexpr float Ix = 0.01f, Iy = 0.01f, Iz = 0.02f;
    constexpr float rIx = 100.0f, rIy = 100.0f, rIz = 50.0f;
    // DT/TAU_M == 1.0f exactly -> thrust update is t += (a*MAX_T - t).

    __shared__ alignas(16) float s_act[HORIZON * 4];  // sigmoid(U)*MAX_T
    __shared__ f32x4 lds4[2][256 * 4];                // 32 KB double buffer

    const int tid = threadIdx.x;
    if (tid < HORIZON * 4) {
        float u = U[tid];
        s_act[tid] = MAX_T / (1.0f + expf(-u));
    }

    // Transpose geometry (verified rounds 2-6).
    const int swzw   = (tid >> 1) & 3;                // own-row chunk XOR
    const int rrow   = tid >> 2;                      // transposed-side row base
    const int rchunk = (tid & 3) ^ ((tid >> 3) & 3);  // transposed-side swizzled chunk

    // ---- staged input load: lane-contiguous global reads -> LDS (transposed) ----
    // Identity: flat float4 index (k*256+tid) == state (k*64 + (tid>>2)), chunk (tid&3),
    // whose swizzled LDS slot is exactly (k*64+rrow)*4 + rchunk.
    const f32x4* inv = reinterpret_cast<const f32x4*>(state_in)
                     + (size_t)blockIdx.x * 1024;
    #pragma unroll
    for (int k = 0; k < 4; ++k)
        lds4[1][(k * 64 + rrow) * 4 + rchunk] = inv[k * 256 + tid];

    __syncthreads();   // covers s_act + input staging

    f32x4* const wb1 = &lds4[1][tid * 4];
    f32x4 s0 = wb1[0 ^ swzw];
    f32x4 s1 = wb1[1 ^ swzw];
    f32x4 s2 = wb1[2 ^ swzw];
    f32x4 s3 = wb1[3 ^ swzw];

    float px = s0.x, py = s0.y, pz = s0.z;
    float vx = s0.w, vy = s1.x, vz = s1.y;
    float phi = s1.z, th = s1.w, psi = s2.x;
    float p = s2.y, q = s2.z, r = s2.w;
    float t0 = s3.x, t1 = s3.y, t2 = s3.z, t3 = s3.w;
    // WAR note: buffer 1 is next written at t==1, which is after step-0's
    // __syncthreads -- every wave's staging reads above precede that barrier.

    f32x4* const outbase = reinterpret_cast<f32x4*>(out)
                         + (size_t)blockIdx.x * 1024;

    #pragma unroll
    for (int t = 0; t < HORIZON; ++t) {
        const f32x4 A = *reinterpret_cast<const f32x4*>(&s_act[t * 4]);

        // rotor thrust first-order lag (dt/tau == 1)
        t0 += A.x - t0;
        t1 += A.y - t1;
        t2 += A.z - t2;
        t3 += A.w - t3;

        const float F    = t0 + t1 + t2 + t3;
        const float taux = ARM * (t0 - t2);
        const float tauy = ARM * (t1 - t3);
        const float tauz = KAPPA * (t0 - t1 + t2 - t3);

        float sphi, cphi, sth, cth, spsi, cpsi;
        __sincosf(phi, &sphi, &cphi);
        __sincosf(th,  &sth,  &cth);
        __sincosf(psi, &spsi, &cpsi);

        const float zbx = cphi * sth * cpsi + sphi * spsi;
        const float zby = cphi * sth * spsi - sphi * cpsi;
        const float zbz = cphi * cth;
        const float ax = F * zbx;          // MASS == 1
        const float ay = F * zby;
        const float az = F * zbz - GRAV;

        const float rcth  = 1.0f / cth;
        const float tanth = sth * rcth;
        const float attd0 = p + sphi * tanth * q + cphi * tanth * r;
        const float attd1 = cphi * q - sphi * r;
        const float attd2 = (sphi * q + cphi * r) * rcth;

        const float hx = Ix * p, hy = Iy * q, hz = Iz * r;
        const float pd = (taux - (q * hz - r * hy)) * rIx;
        const float qd = (tauy - (r * hx - p * hz)) * rIy;
        const float rd = (tauz - (p * hy - q * hx)) * rIz;

        px += DT * vx;  py += DT * vy;  pz += DT * vz;
        vx += DT * ax;  vy += DT * ay;  vz += DT * az;
        phi += DT * attd0;  th += DT * attd1;  psi += DT * attd2;
        p += DT * pd;  q += DT * qd;  r += DT * rd;

        // --- stage this step's state into LDS (swizzled, double-buffered) ---
        const int bb = t & 1;
        f32x4* wb = &lds4[bb][tid * 4];
        wb[0 ^ swzw] = f32x4{px, py, pz, vx};
        wb[1 ^ swzw] = f32x4{vy, vz, phi, th};
        wb[2 ^ swzw] = f32x4{psi, p, q, r};
        wb[3 ^ swzw] = f32x4{t0, t1, t2, t3};
        __syncthreads();

        // --- transposed read-back + lane-contiguous nontemporal stores ---
        f32x4* const op = outbase + (size_t)t * (BATCH * 4);
        #pragma unroll
        for (int k = 0; k < 4; ++k) {
            f32x4 v = lds4[bb][(k * 64 + rrow) * 4 + rchunk];
            __builtin_nontemporal_store(v, op + k * 256 + tid);
        }
    }
}

extern "C" void kernel_launch(void* const* d_in, const int* in_sizes, int n_in,
                              void* d_out, int out_size, void* d_ws, size_t ws_size,
                              hipStream_t stream) {
    const float* state = (const float*)d_in[0];
    const float* U     = (const float*)d_in[1];
    float* out         = (float*)d_out;

    dim3 block(256);
    dim3 grid(BATCH / 256);
    drone_rollout<<<grid, block, 0, stream>>>(state, U, out);
}